// Round 3
// baseline (1987.799 us; speedup 1.0000x reference)
//
#include <hip/hip_runtime.h>
#include <stdint.h>

// ---------------------------------------------------------------------------
// GRU-D (MIMIC) forward. B=512, T=256, D=128, H=128, S=32.
// Phase 0 : pack weights Wcat_t[n][k] bf16 + bias[512]
// Phase 0b: A[m=t*B+b][384] = [x_hat | mask | delta] bf16 (gamma_x folded in)
// Fused   : ONE kernel; blocks 0..31 = sequential scan (16 batch rows each),
//           blocks 32..4127 = GEMM tiles E = A @ Wcat^T in t-ascending order.
//           Producer->consumer sync: per-t counters + monotone watermark
//           (agent-scope atomics; scan caches watermark -> ~free polling).
// E layout: block-local for the scan: E[t][blk=b>>4][n(512)][b&15]
// ---------------------------------------------------------------------------

#define B_ 512
#define T_ 256
#define D_ 128
#define H_ 128
#define S_ 32
#define NE 512   // E width: z(128) r(128) h(128) gamma(128)
#define KA 384   // A width: xhat(128) mask(128) delta(128)
#define M_ (B_*T_)
#define HP 136   // padded LDS row stride (shorts / floats)
#define NSCAN 32
#define ESLAB ((size_t)NE * 16)        // elements per (t,blk) slab = 8192
#define ESTRIDE ((size_t)32 * ESLAB)   // elements per t = 262144

typedef __attribute__((ext_vector_type(8))) short short8;
typedef __attribute__((ext_vector_type(4))) float f32x4;

__device__ __forceinline__ unsigned short f2bf(float f) {
  union { float f; uint32_t u; } v; v.f = f;
  return (unsigned short)((v.u + 0x7FFFu + ((v.u >> 16) & 1u)) >> 16);
}
// cheap round-half-up bf16 (2 VALU ops) — scan LDS stores only
__device__ __forceinline__ unsigned short f2bf_fast(float f) {
  union { float f; uint32_t u; } v; v.f = f;
  return (unsigned short)((v.u + 0x8000u) >> 16);
}
__device__ __forceinline__ float bf2f(uint32_t s) {
  union { uint32_t u; float f; } v; v.u = s << 16;
  return v.f;
}

// raw (packed) E loads + unpack — overloads select bf16 vs fp32 path
__device__ __forceinline__ uint2  ldraw(const unsigned short* p) { return *(const uint2*)p; }
__device__ __forceinline__ float4 ldraw(const float* p)          { return *(const float4*)p; }
__device__ __forceinline__ void unp(uint2 v, float o[4]) {
  o[0] = bf2f(v.x & 0xffffu); o[1] = bf2f(v.x >> 16);
  o[2] = bf2f(v.y & 0xffffu); o[3] = bf2f(v.y >> 16);
}
__device__ __forceinline__ void unp(float4 v, float o[4]) {
  o[0] = v.x; o[1] = v.y; o[2] = v.z; o[3] = v.w;
}
__device__ __forceinline__ void st4(unsigned short* p, const float v[4]) {
  uint2 u;
  u.x = (uint32_t)f2bf(v[0]) | ((uint32_t)f2bf(v[1]) << 16);
  u.y = (uint32_t)f2bf(v[2]) | ((uint32_t)f2bf(v[3]) << 16);
  *(uint2*)p = u;
}
__device__ __forceinline__ void st4(float* p, const float v[4]) {
  *(float4*)p = make_float4(v[0], v[1], v[2], v[3]);
}

__device__ __forceinline__ float fsigmoid(float x) {
  return __builtin_amdgcn_rcpf(1.f + __expf(-x));
}
__device__ __forceinline__ float ftanh(float x) {
  return 1.f - 2.f * __builtin_amdgcn_rcpf(1.f + __expf(2.f * x));
}

#define ASYNC_CP16(gsrc, ldst) \
  __builtin_amdgcn_global_load_lds((const __attribute__((address_space(1))) void*)(gsrc), \
                                   (__attribute__((address_space(3))) void*)(ldst), 16, 0, 0)

// --------------------------------------------------------------------------
__global__ void prep_weights(const float* __restrict__ Wz, const float* __restrict__ Vz,
                             const float* __restrict__ Wr, const float* __restrict__ Vr,
                             const float* __restrict__ Wh, const float* __restrict__ Vh,
                             const float* __restrict__ Wdgh,
                             const float* __restrict__ bz, const float* __restrict__ br,
                             const float* __restrict__ bh, const float* __restrict__ bdgh,
                             unsigned short* __restrict__ Wcat, float* __restrict__ bias)
{
  int id = blockIdx.x * 256 + threadIdx.x;
  if (id < NE * KA) {
    int n = id / KA, k = id - n * KA;
    float v = 0.f;
    if (n < 384) {
      int nn = n & 127;
      const float* W = (n < 128) ? Wz : (n < 256) ? Wr : Wh;
      const float* V = (n < 128) ? Vz : (n < 256) ? Vr : Vh;
      if (k < 128)      v = W[nn * 128 + k];
      else if (k < 256) v = V[nn * 128 + (k - 128)];
    } else {
      if (k >= 256) v = Wdgh[(n - 384) * 128 + (k - 256)];
    }
    Wcat[id] = f2bf(v);
  }
  if (id < NE) {
    bias[id] = (id < 128) ? bz[id] : (id < 256) ? br[id - 128]
             : (id < 384) ? bh[id - 256] : bdgh[id - 384];
  }
}

// --------------------------------------------------------------------------
__global__ void build_A(const float* __restrict__ x, const float* __restrict__ mask,
                        const float* __restrict__ delta, const float* __restrict__ xlast,
                        const float* __restrict__ xmean,
                        const float* __restrict__ wdgx, const float* __restrict__ bdgx,
                        unsigned short* __restrict__ Abuf)
{
  int id = blockIdx.x * 256 + threadIdx.x;  // M_*32 threads, 4 elems each
  int m = id >> 5;
  int c = id & 31;
  int t = m >> 9;
  int b = m & (B_ - 1);
  int k = c * 4;
  size_t src = ((size_t)b * T_ + t) * D_ + k;
  float4 xv = *(const float4*)(x + src);
  float4 mv = *(const float4*)(mask + src);
  float4 dv = *(const float4*)(delta + src);
  float4 lv = *(const float4*)(xlast + src);
  float4 uv = *(const float4*)(xmean + (size_t)b * D_ + k);
  float4 wv = *(const float4*)(wdgx + k);
  float4 bv = *(const float4*)(bdgx + k);
  const float* xp = (const float*)&xv; const float* mp = (const float*)&mv;
  const float* dp = (const float*)&dv; const float* lp = (const float*)&lv;
  const float* up = (const float*)&uv; const float* wp = (const float*)&wv;
  const float* bp = (const float*)&bv;
  unsigned short xh[4], mm[4], dd[4];
  #pragma unroll
  for (int i = 0; i < 4; ++i) {
    float g = __expf(-fmaxf(wp[i] * dp[i] + bp[i], 0.f));
    float xhat = mp[i] * xp[i] + (1.f - mp[i]) * (g * lp[i] + (1.f - g) * up[i]);
    xh[i] = f2bf(xhat); mm[i] = f2bf(mp[i]); dd[i] = f2bf(dp[i]);
  }
  uint2 px, pm, pd;
  px.x = (uint32_t)xh[0] | ((uint32_t)xh[1] << 16); px.y = (uint32_t)xh[2] | ((uint32_t)xh[3] << 16);
  pm.x = (uint32_t)mm[0] | ((uint32_t)mm[1] << 16); pm.y = (uint32_t)mm[2] | ((uint32_t)mm[3] << 16);
  pd.x = (uint32_t)dd[0] | ((uint32_t)dd[1] << 16); pd.y = (uint32_t)dd[2] | ((uint32_t)dd[3] << 16);
  unsigned short* rowp = Abuf + (size_t)m * KA;
  *(uint2*)(rowp + k)       = px;
  *(uint2*)(rowp + 128 + k) = pm;
  *(uint2*)(rowp + 256 + k) = pd;
}

// --------------------------------------------------------------------------
// GEMM role: one 128x128 tile of E. g enumerates t ascending; per t there are
// 16 tiles (4 m-subblocks x 4 n-subblocks).
template <typename ET>
__device__ __forceinline__ void gemm_body(
    int g, char* smem,
    const unsigned short* __restrict__ Abuf, const unsigned short* __restrict__ Wcat,
    const float* __restrict__ bias, ET* __restrict__ E, int* __restrict__ sync)
{
  const int tid = threadIdx.x;
  const int wave = tid >> 6, lane = tid & 63;
  const int q = lane >> 4, rl = lane & 15;
  const int t = g >> 4, sub = g & 15, mi = sub >> 2, ni = sub & 3;
  const int bbase = mi * 128, n0 = ni * 128;
  const size_t arow0 = (size_t)t * B_ + bbase;
  unsigned short* As = (unsigned short*)smem;
  unsigned short* Bs = As + 4096;
  const int wr = (wave >> 2) * 64, wc = (wave & 3) * 32;   // wave tile 64x32
  const int srow = tid >> 2, skc = tid & 3;

  f32x4 acc[4][2];
  #pragma unroll
  for (int a = 0; a < 4; ++a)
    #pragma unroll
    for (int b = 0; b < 2; ++b) acc[a][b] = (f32x4){0.f, 0.f, 0.f, 0.f};

  for (int kt = 0; kt < KA / 32; ++kt) {
    const int kbase = kt * 32;
    ASYNC_CP16(Abuf + (arow0 + srow) * KA + kbase + skc * 8, As + (size_t)tid * 8);
    ASYNC_CP16(Wcat + (size_t)(n0 + srow) * KA + kbase + skc * 8, Bs + (size_t)tid * 8);
    __syncthreads();
    short8 af[4], bfr[2];
    #pragma unroll
    for (int tm = 0; tm < 4; ++tm)
      af[tm] = *(const short8*)(As + (wr + tm * 16 + rl) * 32 + q * 8);
    #pragma unroll
    for (int tn = 0; tn < 2; ++tn)
      bfr[tn] = *(const short8*)(Bs + (wc + tn * 16 + rl) * 32 + q * 8);
    #pragma unroll
    for (int tm = 0; tm < 4; ++tm)
      #pragma unroll
      for (int tn = 0; tn < 2; ++tn)
        acc[tm][tn] = __builtin_amdgcn_mfma_f32_16x16x32_bf16(af[tm], bfr[tn], acc[tm][tn], 0, 0, 0);
    __syncthreads();
  }

  // epilogue: write E in block-local scan layout E[t][b>>4][n][b&15]
  #pragma unroll
  for (int tn = 0; tn < 2; ++tn) {
    int n = n0 + wc + tn * 16 + rl;
    float bv = bias[n];
    bool isg = (n >= 384);
    #pragma unroll
    for (int tm = 0; tm < 4; ++tm) {
      int brow = bbase + wr + tm * 16;     // multiple of 16
      float v[4];
      #pragma unroll
      for (int reg = 0; reg < 4; ++reg) {
        float xv = acc[tm][tn][reg] + bv;
        v[reg] = isg ? __expf(-fmaxf(xv, 0.f)) : xv;
      }
      st4(E + ((size_t)t * 32 + (brow >> 4)) * ESLAB + (size_t)n * 16 + q * 4, v);
    }
  }
  __syncthreads();                    // all waves' stores drained (vmcnt)
  if (tid == 0) {
    // release: L2 writeback + L3-scope add; 16th finisher advances watermark
    int old = __hip_atomic_fetch_add(&sync[t], 1, __ATOMIC_ACQ_REL, __HIP_MEMORY_SCOPE_AGENT);
    if (old == 15) {
      int* wmp = sync + T_;
      while (__hip_atomic_load(wmp, __ATOMIC_ACQUIRE, __HIP_MEMORY_SCOPE_AGENT) < t)
        __builtin_amdgcn_s_sleep(4);
      __hip_atomic_store(wmp, t + 1, __ATOMIC_RELEASE, __HIP_MEMORY_SCOPE_AGENT);
    }
  }
}

// --------------------------------------------------------------------------
template <typename ET>
__global__ __launch_bounds__(512, 2) void fused_gemm_scan(
    const unsigned short* __restrict__ Abuf, const unsigned short* __restrict__ Wcat,
    const float* __restrict__ bias, ET* __restrict__ E, int* __restrict__ sync,
    const float* __restrict__ Uz, const float* __restrict__ Ur, const float* __restrict__ Uh,
    const float* __restrict__ hs0, const float* __restrict__ statics,
    const float* __restrict__ Wout, const float* __restrict__ bout,
    float* __restrict__ out)
{
  __shared__ __align__(16) char smem[17408];
  if (blockIdx.x >= NSCAN) {
    gemm_body<ET>(blockIdx.x - NSCAN, smem, Abuf, Wcat, bias, E, sync);
    return;
  }

  // ------------------------------ scan role ------------------------------
  unsigned short* hdec = (unsigned short*)smem;        // 16*HP shorts
  unsigned short* rhb  = hdec + 16 * HP;               // 16*HP shorts
  float* hfin = (float*)(smem + 4 * 16 * HP);          // 16*HP floats
  int* wmp = sync + T_;                                // watermark: slabs [0,wm) done
  const int tid = threadIdx.x;
  const int wave = tid >> 6, lane = tid & 63;
  const int q = lane >> 4, rl = lane & 15;
  const int col = wave * 16 + rl;       // H column this lane owns (C/D + B-frag)
  const int b0 = blockIdx.x * 16;

  // U_* as resident B-fragments: B[k][n]=U[n][k]; lane: n=col, k=kc*32+q*8+j
  short8 uz[4], ur[4], uh[4];
  #pragma unroll
  for (int kc = 0; kc < 4; ++kc) {
    int koff = kc * 32 + q * 8;
    const float* pzw = Uz + col * H_ + koff;
    const float* prw = Ur + col * H_ + koff;
    const float* phw = Uh + col * H_ + koff;
    #pragma unroll
    for (int j = 0; j < 8; ++j) {
      uz[kc][j] = (short)f2bf(pzw[j]);
      ur[kc][j] = (short)f2bf(prw[j]);
      uh[kc][j] = (short)f2bf(phw[j]);
    }
  }

  // per-lane E pointers (block-local layout): slab = blk*ESLAB, +n*16 + q*4
  const ET* pz = E + (size_t)blockIdx.x * ESLAB + (size_t)col * 16 + q * 4;
  const ET* pr = pz + 128 * 16;
  const ET* ph = pz + 256 * 16;
  const ET* pg = pz + 384 * 16;

  // wait for slabs 0,1
  int cw = __hip_atomic_load(wmp, __ATOMIC_ACQUIRE, __HIP_MEMORY_SCOPE_AGENT);
  while (cw < 2) {
    __builtin_amdgcn_s_sleep(8);
    cw = __hip_atomic_load(wmp, __ATOMIC_ACQUIRE, __HIP_MEMORY_SCOPE_AGENT);
  }

  using RawT = decltype(ldraw((const ET*)nullptr));
  RawT cz, cr, chh, cg, nz{}, nr{}, nh{}, ng{};
  cz  = ldraw(pz);                 // slab t=0
  cr  = ldraw(pr);
  chh = ldraw(ph);
  cg  = ldraw(pg + ESTRIDE);       // gamma for step 0's epilogue = slab 1
  RawT g0raw = ldraw(pg);          // gamma at t=0 for h-init

  // h state (fp32) in C/D layout: rows q*4+reg, col
  float hd[4], g0[4];
  unp(g0raw, g0);
  #pragma unroll
  for (int reg = 0; reg < 4; ++reg) {
    int row = q * 4 + reg;
    float h0 = hs0[(b0 + row) * H_ + col];
    hd[reg] = g0[reg] * h0;
    hdec[row * HP + col] = f2bf_fast(hd[reg]);
  }
  __syncthreads();

  for (int t = 0; t < T_; ++t) {
    // ---- wait + prefetch E for step t+1 (and gamma for t+2) ----
    if (t + 1 < T_) {
      const int need = (t + 2 < T_) ? (t + 3) : (t + 2);  // wm must exceed max slab touched
      while (cw < need) {
        cw = __hip_atomic_load(wmp, __ATOMIC_ACQUIRE, __HIP_MEMORY_SCOPE_AGENT);
        if (cw < need) __builtin_amdgcn_s_sleep(8);
      }
      size_t off = (size_t)(t + 1) * ESTRIDE;
      nz = ldraw(pz + off); nr = ldraw(pr + off); nh = ldraw(ph + off);
      if (t + 2 < T_) ng = ldraw(pg + (size_t)(t + 2) * ESTRIDE);
    }
    float Pz[4], Pr[4], Ph[4];
    unp(cz, Pz); unp(cr, Pr); unp(chh, Ph);

    // A-frags of decayed h from LDS
    short8 af[4];
    #pragma unroll
    for (int kc = 0; kc < 4; ++kc)
      af[kc] = *(const short8*)(&hdec[rl * HP + kc * 32 + q * 8]);
    f32x4 accz = (f32x4){0.f,0.f,0.f,0.f}, accr = (f32x4){0.f,0.f,0.f,0.f};
    #pragma unroll
    for (int kc = 0; kc < 4; ++kc) {
      accz = __builtin_amdgcn_mfma_f32_16x16x32_bf16(af[kc], uz[kc], accz, 0, 0, 0);
      accr = __builtin_amdgcn_mfma_f32_16x16x32_bf16(af[kc], ur[kc], accr, 0, 0, 0);
    }
    float zz[4];
    #pragma unroll
    for (int reg = 0; reg < 4; ++reg) {
      zz[reg] = fsigmoid(accz[reg] + Pz[reg]);
      float rr = fsigmoid(accr[reg] + Pr[reg]);
      rhb[(q * 4 + reg) * HP + col] = f2bf_fast(rr * hd[reg]);
    }
    __syncthreads();                                   // barrier 1

    short8 ar[4];
    #pragma unroll
    for (int kc = 0; kc < 4; ++kc)
      ar[kc] = *(const short8*)(&rhb[rl * HP + kc * 32 + q * 8]);
    f32x4 acch = (f32x4){0.f,0.f,0.f,0.f};
    #pragma unroll
    for (int kc = 0; kc < 4; ++kc)
      acch = __builtin_amdgcn_mfma_f32_16x16x32_bf16(ar[kc], uh[kc], acch, 0, 0, 0);

    if (t < T_ - 1) {
      float Gn[4];
      unp(cg, Gn);
      #pragma unroll
      for (int reg = 0; reg < 4; ++reg) {
        float ht = ftanh(acch[reg] + Ph[reg]);
        float hn = hd[reg] + zz[reg] * (ht - hd[reg]);   // (1-z)h + z*h~
        hd[reg] = Gn[reg] * hn;                          // fold next-step decay
        hdec[(q * 4 + reg) * HP + col] = f2bf_fast(hd[reg]);
      }
    } else {
      #pragma unroll
      for (int reg = 0; reg < 4; ++reg) {
        float ht = ftanh(acch[reg] + Ph[reg]);
        float hn = hd[reg] + zz[reg] * (ht - hd[reg]);
        hfin[(q * 4 + reg) * HP + col] = hn;
      }
    }
    __syncthreads();                                   // barrier 2

    cz = nz; cr = nr; chh = nh; cg = ng;
  }

  // fused classifier: 32 threads per batch row
  {
    int row = tid >> 5, j = tid & 31;
    float acc = 0.f;
    #pragma unroll
    for (int c0 = 0; c0 < 4; ++c0)
      acc += hfin[row * HP + j + c0 * 32] * Wout[j + c0 * 32];
    acc += statics[(size_t)(b0 + row) * S_ + j] * Wout[H_ + j];
    #pragma unroll
    for (int off = 16; off >= 1; off >>= 1)
      acc += __shfl_down(acc, off, 32);
    if (j == 0) out[b0 + row] = acc + bout[0];
  }
}

// --------------------------------------------------------------------------
template <typename ET>
static void launch_all(void* const* d_in, float* out, char* ws, hipStream_t stream)
{
  const float* x      = (const float*)d_in[0];
  const float* statics= (const float*)d_in[1];
  const float* mask   = (const float*)d_in[2];
  const float* delta  = (const float*)d_in[3];
  const float* xlast  = (const float*)d_in[4];
  const float* xmean  = (const float*)d_in[5];
  const float* hs0    = (const float*)d_in[6];
  const float* wdgx   = (const float*)d_in[7];
  const float* bdgx   = (const float*)d_in[8];
  const float* Wdgh   = (const float*)d_in[9];
  const float* bdgh   = (const float*)d_in[10];
  const float* Wz     = (const float*)d_in[11];
  const float* Uz     = (const float*)d_in[12];
  const float* Vz     = (const float*)d_in[13];
  const float* bz     = (const float*)d_in[14];
  const float* Wr     = (const float*)d_in[15];
  const float* Ur     = (const float*)d_in[16];
  const float* Vr     = (const float*)d_in[17];
  const float* br     = (const float*)d_in[18];
  const float* Wh     = (const float*)d_in[19];
  const float* Uh     = (const float*)d_in[20];
  const float* Vh     = (const float*)d_in[21];
  const float* bh     = (const float*)d_in[22];
  const float* Wout   = (const float*)d_in[23];
  const float* bout   = (const float*)d_in[24];

  const size_t eBytes = (size_t)M_ * NE * sizeof(ET);
  const size_t aBytes = (size_t)M_ * KA * 2;
  const size_t wBytes = (size_t)NE * KA * 2;
  ET* E = (ET*)ws;
  unsigned short* Abuf = (unsigned short*)(ws + eBytes);
  unsigned short* Wcat = (unsigned short*)(ws + eBytes + aBytes);
  float* bias = (float*)(ws + eBytes + aBytes + wBytes);
  int* sync = (int*)(ws + eBytes + aBytes + wBytes + 2048);   // cnt[256] + wm

  prep_weights<<<768, 256, 0, stream>>>(Wz, Vz, Wr, Vr, Wh, Vh, Wdgh,
                                        bz, br, bh, bdgh, Wcat, bias);
  build_A<<<(M_ * 32) / 256, 256, 0, stream>>>(x, mask, delta, xlast, xmean,
                                               wdgx, bdgx, Abuf);
  hipMemsetAsync(sync, 0, (T_ + 1) * sizeof(int), stream);
  fused_gemm_scan<ET><<<NSCAN + 16 * T_, 512, 0, stream>>>(
      Abuf, Wcat, bias, E, sync, Uz, Ur, Uh, hs0, statics, Wout, bout, out);
}

extern "C" void kernel_launch(void* const* d_in, const int* in_sizes, int n_in,
                              void* d_out, int out_size, void* d_ws, size_t ws_size,
                              hipStream_t stream)
{
  char* ws = (char*)d_ws;
  float* out = (float*)d_out;
  const size_t common = (size_t)M_ * KA * 2 + (size_t)NE * KA * 2 + 8192;
  const size_t needF32 = (size_t)M_ * NE * 4 + common;   // ~352 MB
  const size_t needBF  = (size_t)M_ * NE * 2 + common;   // ~224 MB
  if (ws_size >= needF32)     launch_all<float>(d_in, out, ws, stream);
  else if (ws_size >= needBF) launch_all<unsigned short>(d_in, out, ws, stream);
  // else: workspace too small for any path — launch nothing (fails visibly)
}

// Round 4
// 597.464 us; speedup vs baseline: 3.3271x; 3.3271x over previous
//
#include <hip/hip_runtime.h>
#include <stdint.h>

// ---------------------------------------------------------------------------
// GRU-D (MIMIC) forward. B=512, T=256, D=128, H=128, S=32.
// Phase 0 : pack weights Wcat_t[n][k] bf16 + bias[512]
// Phase 0b: A[m=t*B+b][384] = [x_hat | mask | delta] bf16 (gamma_x folded in)
// Phase 1 : E = A @ Wcat^T (+bias; cols>=384 -> exp(-relu)) via MFMA.
//           3-deep software-pipelined global_load_lds staging (vmcnt(4) waits,
//           raw s_barrier -- no full vmcnt(0) drain per K-iter).
//           E stored block-local for the scan: E[t][blk=b>>4][n(512)][b&15]
// Phase 2 : sequential scan, 32 blocks x 16 batch rows; vectorized E loads
//           prefetched one step ahead; raw lgkm-only barriers (no vmcnt
//           drain of the prefetch); rcp-based sigmoid/tanh; classifier fused.
// NOTE (round 3 post-mortem): fused producer/consumer with agent-scope
// ACQ_REL atomics regressed 3.3x -- each release = L2 writeback; 4096 of
// them flushed E to HBM and serialized the L2s. Keep phases as separate
// dispatches; the kernel-boundary flush is paid once, not 4096 times.
// ---------------------------------------------------------------------------

#define B_ 512
#define T_ 256
#define D_ 128
#define H_ 128
#define S_ 32
#define NE 512   // E width: z(128) r(128) h(128) gamma(128)
#define KA 384   // A width: xhat(128) mask(128) delta(128)
#define M_ (B_*T_)
#define HP 136   // padded LDS row stride (shorts / floats)
#define ESLAB ((size_t)NE * 16)        // elements per (t,blk) slab = 8192
#define ESTRIDE ((size_t)32 * ESLAB)   // elements per t = 262144

typedef __attribute__((ext_vector_type(8))) short short8;
typedef __attribute__((ext_vector_type(4))) float f32x4;

// raw barrier: LDS visibility only (lgkm drain), no vmcnt(0) drain of
// in-flight global prefetches (which __syncthreads would force).
#define BAR_LDS() asm volatile("s_waitcnt lgkmcnt(0)\n\ts_barrier" ::: "memory")

__device__ __forceinline__ unsigned short f2bf(float f) {
  union { float f; uint32_t u; } v; v.f = f;
  return (unsigned short)((v.u + 0x7FFFu + ((v.u >> 16) & 1u)) >> 16);
}
// cheap round-half-up bf16 (2 VALU ops) — scan LDS stores only
__device__ __forceinline__ unsigned short f2bf_fast(float f) {
  union { float f; uint32_t u; } v; v.f = f;
  return (unsigned short)((v.u + 0x8000u) >> 16);
}
__device__ __forceinline__ float bf2f(uint32_t s) {
  union { uint32_t u; float f; } v; v.u = s << 16;
  return v.f;
}

// raw (packed) E loads + unpack — overloads select bf16 vs fp32 path
__device__ __forceinline__ uint2  ldraw(const unsigned short* p) { return *(const uint2*)p; }
__device__ __forceinline__ float4 ldraw(const float* p)          { return *(const float4*)p; }
__device__ __forceinline__ void unp(uint2 v, float o[4]) {
  o[0] = bf2f(v.x & 0xffffu); o[1] = bf2f(v.x >> 16);
  o[2] = bf2f(v.y & 0xffffu); o[3] = bf2f(v.y >> 16);
}
__device__ __forceinline__ void unp(float4 v, float o[4]) {
  o[0] = v.x; o[1] = v.y; o[2] = v.z; o[3] = v.w;
}
__device__ __forceinline__ void st4(unsigned short* p, const float v[4]) {
  uint2 u;
  u.x = (uint32_t)f2bf(v[0]) | ((uint32_t)f2bf(v[1]) << 16);
  u.y = (uint32_t)f2bf(v[2]) | ((uint32_t)f2bf(v[3]) << 16);
  *(uint2*)p = u;
}
__device__ __forceinline__ void st4(float* p, const float v[4]) {
  *(float4*)p = make_float4(v[0], v[1], v[2], v[3]);
}

__device__ __forceinline__ float fsigmoid(float x) {
  return __builtin_amdgcn_rcpf(1.f + __expf(-x));
}
__device__ __forceinline__ float ftanh(float x) {
  return 1.f - 2.f * __builtin_amdgcn_rcpf(1.f + __expf(2.f * x));
}

#define ASYNC_CP16(gsrc, ldst) \
  __builtin_amdgcn_global_load_lds((const __attribute__((address_space(1))) void*)(gsrc), \
                                   (__attribute__((address_space(3))) void*)(ldst), 16, 0, 0)

// --------------------------------------------------------------------------
__global__ void prep_weights(const float* __restrict__ Wz, const float* __restrict__ Vz,
                             const float* __restrict__ Wr, const float* __restrict__ Vr,
                             const float* __restrict__ Wh, const float* __restrict__ Vh,
                             const float* __restrict__ Wdgh,
                             const float* __restrict__ bz, const float* __restrict__ br,
                             const float* __restrict__ bh, const float* __restrict__ bdgh,
                             unsigned short* __restrict__ Wcat, float* __restrict__ bias)
{
  int id = blockIdx.x * 256 + threadIdx.x;
  if (id < NE * KA) {
    int n = id / KA, k = id - n * KA;
    float v = 0.f;
    if (n < 384) {
      int nn = n & 127;
      const float* W = (n < 128) ? Wz : (n < 256) ? Wr : Wh;
      const float* V = (n < 128) ? Vz : (n < 256) ? Vr : Vh;
      if (k < 128)      v = W[nn * 128 + k];
      else if (k < 256) v = V[nn * 128 + (k - 128)];
    } else {
      if (k >= 256) v = Wdgh[(n - 384) * 128 + (k - 256)];
    }
    Wcat[id] = f2bf(v);
  }
  if (id < NE) {
    bias[id] = (id < 128) ? bz[id] : (id < 256) ? br[id - 128]
             : (id < 384) ? bh[id - 256] : bdgh[id - 384];
  }
}

// --------------------------------------------------------------------------
__global__ void build_A(const float* __restrict__ x, const float* __restrict__ mask,
                        const float* __restrict__ delta, const float* __restrict__ xlast,
                        const float* __restrict__ xmean,
                        const float* __restrict__ wdgx, const float* __restrict__ bdgx,
                        unsigned short* __restrict__ Abuf)
{
  int id = blockIdx.x * 256 + threadIdx.x;  // M_*32 threads, 4 elems each
  int m = id >> 5;
  int c = id & 31;
  int t = m >> 9;
  int b = m & (B_ - 1);
  int k = c * 4;
  size_t src = ((size_t)b * T_ + t) * D_ + k;
  float4 xv = *(const float4*)(x + src);
  float4 mv = *(const float4*)(mask + src);
  float4 dv = *(const float4*)(delta + src);
  float4 lv = *(const float4*)(xlast + src);
  float4 uv = *(const float4*)(xmean + (size_t)b * D_ + k);
  float4 wv = *(const float4*)(wdgx + k);
  float4 bv = *(const float4*)(bdgx + k);
  const float* xp = (const float*)&xv; const float* mp = (const float*)&mv;
  const float* dp = (const float*)&dv; const float* lp = (const float*)&lv;
  const float* up = (const float*)&uv; const float* wp = (const float*)&wv;
  const float* bp = (const float*)&bv;
  unsigned short xh[4], mm[4], dd[4];
  #pragma unroll
  for (int i = 0; i < 4; ++i) {
    float g = __expf(-fmaxf(wp[i] * dp[i] + bp[i], 0.f));
    float xhat = mp[i] * xp[i] + (1.f - mp[i]) * (g * lp[i] + (1.f - g) * up[i]);
    xh[i] = f2bf(xhat); mm[i] = f2bf(mp[i]); dd[i] = f2bf(dp[i]);
  }
  uint2 px, pm, pd;
  px.x = (uint32_t)xh[0] | ((uint32_t)xh[1] << 16); px.y = (uint32_t)xh[2] | ((uint32_t)xh[3] << 16);
  pm.x = (uint32_t)mm[0] | ((uint32_t)mm[1] << 16); pm.y = (uint32_t)mm[2] | ((uint32_t)mm[3] << 16);
  pd.x = (uint32_t)dd[0] | ((uint32_t)dd[1] << 16); pd.y = (uint32_t)dd[2] | ((uint32_t)dd[3] << 16);
  unsigned short* rowp = Abuf + (size_t)m * KA;
  *(uint2*)(rowp + k)       = px;
  *(uint2*)(rowp + 128 + k) = pm;
  *(uint2*)(rowp + 256 + k) = pd;
}

// --------------------------------------------------------------------------
// 128x128 tile, K=384 in 12 iters of 32. 3-buffer async pipeline:
// iter kt: wait vmcnt(4) [stage kt done, stage kt+1 in flight], s_barrier,
// issue stage(kt+2), MFMA on buf kt%3. 4 loads/thread/stage.
template <typename ET>
__global__ __launch_bounds__(256, 2) void gemm_phase1(
    const unsigned short* __restrict__ Abuf, const unsigned short* __restrict__ Wcat,
    const float* __restrict__ bias, ET* __restrict__ E)
{
  __shared__ unsigned short As[3][4096];
  __shared__ unsigned short Bs[3][4096];
  const int tid = threadIdx.x;
  const int wave = tid >> 6, lane = tid & 63;
  const int q = lane >> 4, rl = lane & 15;
  const int m0 = blockIdx.x * 128;
  const int n0 = blockIdx.y * 128;
  const int wm = (wave >> 1) * 64, wn = (wave & 1) * 64;

  f32x4 acc[4][4];
  #pragma unroll
  for (int a = 0; a < 4; ++a)
    #pragma unroll
    for (int b = 0; b < 4; ++b) acc[a][b] = (f32x4){0.f, 0.f, 0.f, 0.f};

  // stage(kt): copy A/B 128x32 bf16 tiles for k-slice kt into buffer kt%3
  #define STAGE(kt_) do {                                                     \
    const int kbase_ = (kt_) * 32; const int buf_ = (kt_) % 3;                \
    _Pragma("unroll")                                                         \
    for (int i = 0; i < 2; ++i) {                                             \
      int chunk = i * 256 + wave * 64 + lane;                                 \
      int row = chunk >> 2, kc = chunk & 3;                                   \
      ASYNC_CP16(Abuf + (size_t)(m0 + row) * KA + kbase_ + kc * 8,            \
                 &As[buf_][(i * 256 + wave * 64) * 8]);                       \
      ASYNC_CP16(Wcat + (size_t)(n0 + row) * KA + kbase_ + kc * 8,            \
                 &Bs[buf_][(i * 256 + wave * 64) * 8]);                       \
    }                                                                         \
  } while (0)

  STAGE(0);
  STAGE(1);

  #pragma unroll
  for (int kt = 0; kt < 12; ++kt) {
    if (kt == 11) asm volatile("s_waitcnt vmcnt(0)" ::: "memory");
    else          asm volatile("s_waitcnt vmcnt(4)" ::: "memory");
    asm volatile("s_barrier" ::: "memory");
    if (kt < 10) STAGE(kt + 2);
    const int buf = kt % 3;
    short8 af[4], bfr[4];
    #pragma unroll
    for (int tm = 0; tm < 4; ++tm)
      af[tm] = *(const short8*)(&As[buf][(wm + tm * 16 + rl) * 32 + q * 8]);
    #pragma unroll
    for (int tn = 0; tn < 4; ++tn)
      bfr[tn] = *(const short8*)(&Bs[buf][(wn + tn * 16 + rl) * 32 + q * 8]);
    #pragma unroll
    for (int tm = 0; tm < 4; ++tm)
      #pragma unroll
      for (int tn = 0; tn < 4; ++tn)
        acc[tm][tn] = __builtin_amdgcn_mfma_f32_16x16x32_bf16(af[tm], bfr[tn], acc[tm][tn], 0, 0, 0);
  }
  #undef STAGE

  // epilogue: write E in block-local scan layout E[t][b>>4][n][b&15]
  const int t = m0 >> 9;             // constant per block
  const int bbase = m0 & (B_ - 1);
  #pragma unroll
  for (int tn = 0; tn < 4; ++tn) {
    int n = n0 + wn + tn * 16 + rl;
    float bv = bias[n];
    bool isg = (n >= 384);
    #pragma unroll
    for (int tm = 0; tm < 4; ++tm) {
      int brow = bbase + wm + tm * 16;     // multiple of 16
      float v[4];
      #pragma unroll
      for (int reg = 0; reg < 4; ++reg) {
        float xv = acc[tm][tn][reg] + bv;
        v[reg] = isg ? __expf(-fmaxf(xv, 0.f)) : xv;
      }
      st4(E + ((size_t)t * 32 + (brow >> 4)) * ESLAB + (size_t)n * 16 + q * 4, v);
    }
  }
}

// --------------------------------------------------------------------------
template <typename ET>
__global__ __launch_bounds__(512, 2) void grud_scan(
    const ET* __restrict__ E,
    const float* __restrict__ Uz, const float* __restrict__ Ur, const float* __restrict__ Uh,
    const float* __restrict__ hs0, const float* __restrict__ statics,
    const float* __restrict__ Wout, const float* __restrict__ bout,
    float* __restrict__ out)
{
  __shared__ unsigned short hdec[16 * HP];
  __shared__ unsigned short rhb[16 * HP];
  __shared__ float hfin[16 * HP];
  const int tid = threadIdx.x;
  const int wave = tid >> 6, lane = tid & 63;
  const int q = lane >> 4, rl = lane & 15;
  const int col = wave * 16 + rl;       // H column this lane owns (C/D + B-frag)
  const int b0 = blockIdx.x * 16;

  // U_* as resident B-fragments: B[k][n]=U[n][k]; lane: n=col, k=kc*32+q*8+j
  short8 uz[4], ur[4], uh[4];
  #pragma unroll
  for (int kc = 0; kc < 4; ++kc) {
    int koff = kc * 32 + q * 8;
    const float* pzw = Uz + col * H_ + koff;
    const float* prw = Ur + col * H_ + koff;
    const float* phw = Uh + col * H_ + koff;
    #pragma unroll
    for (int j = 0; j < 8; ++j) {
      uz[kc][j] = (short)f2bf(pzw[j]);
      ur[kc][j] = (short)f2bf(prw[j]);
      uh[kc][j] = (short)f2bf(phw[j]);
    }
  }

  // per-lane E pointers (block-local layout): slab = blk*ESLAB, +n*16 + q*4
  const ET* pz = E + (size_t)blockIdx.x * ESLAB + (size_t)col * 16 + q * 4;
  const ET* pr = pz + 128 * 16;
  const ET* ph = pz + 256 * 16;
  const ET* pg = pz + 384 * 16;

  using RawT = decltype(ldraw((const ET*)nullptr));
  RawT cz, cr, chh, cg, nz{}, nr{}, nh{}, ng{};
  cz  = ldraw(pz);                 // slab t=0
  cr  = ldraw(pr);
  chh = ldraw(ph);
  cg  = ldraw(pg + ESTRIDE);       // gamma for step 0's epilogue = slab 1
  RawT g0raw = ldraw(pg);          // gamma at t=0 for h-init

  // h state (fp32) in C/D layout: rows q*4+reg, col
  float hd[4], g0[4];
  unp(g0raw, g0);
  #pragma unroll
  for (int reg = 0; reg < 4; ++reg) {
    int row = q * 4 + reg;
    float h0 = hs0[(b0 + row) * H_ + col];
    hd[reg] = g0[reg] * h0;
    hdec[row * HP + col] = f2bf_fast(hd[reg]);
  }
  BAR_LDS();

  for (int t = 0; t < T_; ++t) {
    // ---- prefetch E for step t+1 (and gamma for t+2) ----
    if (t + 1 < T_) {
      size_t off = (size_t)(t + 1) * ESTRIDE;
      nz = ldraw(pz + off); nr = ldraw(pr + off); nh = ldraw(ph + off);
      if (t + 2 < T_) ng = ldraw(pg + (size_t)(t + 2) * ESTRIDE);
    }
    float Pz[4], Pr[4], Ph[4];
    unp(cz, Pz); unp(cr, Pr); unp(chh, Ph);

    // A-frags of decayed h from LDS
    short8 af[4];
    #pragma unroll
    for (int kc = 0; kc < 4; ++kc)
      af[kc] = *(const short8*)(&hdec[rl * HP + kc * 32 + q * 8]);
    f32x4 accz = (f32x4){0.f,0.f,0.f,0.f}, accr = (f32x4){0.f,0.f,0.f,0.f};
    #pragma unroll
    for (int kc = 0; kc < 4; ++kc) {
      accz = __builtin_amdgcn_mfma_f32_16x16x32_bf16(af[kc], uz[kc], accz, 0, 0, 0);
      accr = __builtin_amdgcn_mfma_f32_16x16x32_bf16(af[kc], ur[kc], accr, 0, 0, 0);
    }
    float zz[4];
    #pragma unroll
    for (int reg = 0; reg < 4; ++reg) {
      zz[reg] = fsigmoid(accz[reg] + Pz[reg]);
      float rr = fsigmoid(accr[reg] + Pr[reg]);
      rhb[(q * 4 + reg) * HP + col] = f2bf_fast(rr * hd[reg]);
    }
    BAR_LDS();                                         // barrier 1

    short8 ar[4];
    #pragma unroll
    for (int kc = 0; kc < 4; ++kc)
      ar[kc] = *(const short8*)(&rhb[rl * HP + kc * 32 + q * 8]);
    f32x4 acch = (f32x4){0.f,0.f,0.f,0.f};
    #pragma unroll
    for (int kc = 0; kc < 4; ++kc)
      acch = __builtin_amdgcn_mfma_f32_16x16x32_bf16(ar[kc], uh[kc], acch, 0, 0, 0);

    if (t < T_ - 1) {
      float Gn[4];
      unp(cg, Gn);
      #pragma unroll
      for (int reg = 0; reg < 4; ++reg) {
        float ht = ftanh(acch[reg] + Ph[reg]);
        float hn = hd[reg] + zz[reg] * (ht - hd[reg]);   // (1-z)h + z*h~
        hd[reg] = Gn[reg] * hn;                          // fold next-step decay
        hdec[(q * 4 + reg) * HP + col] = f2bf_fast(hd[reg]);
      }
    } else {
      #pragma unroll
      for (int reg = 0; reg < 4; ++reg) {
        float ht = ftanh(acch[reg] + Ph[reg]);
        float hn = hd[reg] + zz[reg] * (ht - hd[reg]);
        hfin[(q * 4 + reg) * HP + col] = hn;
      }
    }
    BAR_LDS();                                         // barrier 2

    cz = nz; cr = nr; chh = nh; cg = ng;
  }

  // fused classifier: 32 threads per batch row
  {
    int row = tid >> 5, j = tid & 31;
    float acc = 0.f;
    #pragma unroll
    for (int c0 = 0; c0 < 4; ++c0)
      acc += hfin[row * HP + j + c0 * 32] * Wout[j + c0 * 32];
    acc += statics[(size_t)(b0 + row) * S_ + j] * Wout[H_ + j];
    #pragma unroll
    for (int off = 16; off >= 1; off >>= 1)
      acc += __shfl_down(acc, off, 32);
    if (j == 0) out[b0 + row] = acc + bout[0];
  }
}

// --------------------------------------------------------------------------
template <typename ET>
static void launch_all(void* const* d_in, float* out, char* ws, hipStream_t stream)
{
  const float* x      = (const float*)d_in[0];
  const float* statics= (const float*)d_in[1];
  const float* mask   = (const float*)d_in[2];
  const float* delta  = (const float*)d_in[3];
  const float* xlast  = (const float*)d_in[4];
  const float* xmean  = (const float*)d_in[5];
  const float* hs0    = (const float*)d_in[6];
  const float* wdgx   = (const float*)d_in[7];
  const float* bdgx   = (const float*)d_in[8];
  const float* Wdgh   = (const float*)d_in[9];
  const float* bdgh   = (const float*)d_in[10];
  const float* Wz     = (const float*)d_in[11];
  const float* Uz     = (const float*)d_in[12];
  const float* Vz     = (const float*)d_in[13];
  const float* bz     = (const float*)d_in[14];
  const float* Wr     = (const float*)d_in[15];
  const float* Ur     = (const float*)d_in[16];
  const float* Vr     = (const float*)d_in[17];
  const float* br     = (const float*)d_in[18];
  const float* Wh     = (const float*)d_in[19];
  const float* Uh     = (const float*)d_in[20];
  const float* Vh     = (const float*)d_in[21];
  const float* bh     = (const float*)d_in[22];
  const float* Wout   = (const float*)d_in[23];
  const float* bout   = (const float*)d_in[24];

  const size_t eBytes = (size_t)M_ * NE * sizeof(ET);
  const size_t aBytes = (size_t)M_ * KA * 2;
  const size_t wBytes = (size_t)NE * KA * 2;
  ET* E = (ET*)ws;
  unsigned short* Abuf = (unsigned short*)(ws + eBytes);
  unsigned short* Wcat = (unsigned short*)(ws + eBytes + aBytes);
  float* bias = (float*)(ws + eBytes + aBytes + wBytes);

  prep_weights<<<768, 256, 0, stream>>>(Wz, Vz, Wr, Vr, Wh, Vh, Wdgh,
                                        bz, br, bh, bdgh, Wcat, bias);
  build_A<<<(M_ * 32) / 256, 256, 0, stream>>>(x, mask, delta, xlast, xmean,
                                               wdgx, bdgx, Abuf);
  gemm_phase1<ET><<<dim3(M_ / 128, NE / 128), 256, 0, stream>>>(Abuf, Wcat, bias, E);
  grud_scan<ET><<<B_ / 16, 512, 0, stream>>>(E, Uz, Ur, Uh, hs0, statics, Wout, bout, out);
}

extern "C" void kernel_launch(void* const* d_in, const int* in_sizes, int n_in,
                              void* d_out, int out_size, void* d_ws, size_t ws_size,
                              hipStream_t stream)
{
  char* ws = (char*)d_ws;
  float* out = (float*)d_out;
  const size_t common = (size_t)M_ * KA * 2 + (size_t)NE * KA * 2 + 8192;
  const size_t needF32 = (size_t)M_ * NE * 4 + common;   // ~352 MB
  const size_t needBF  = (size_t)M_ * NE * 2 + common;   // ~224 MB
  if (ws_size >= needF32)     launch_all<float>(d_in, out, ws, stream);
  else if (ws_size >= needBF) launch_all<unsigned short>(d_in, out, ws, stream);
  // else: workspace too small for any path — launch nothing (fails visibly)
}